// Round 1
// baseline (145.768 us; speedup 1.0000x reference)
//
#include <hip/hip_runtime.h>
#include <hip/hip_bf16.h>
#include <math.h>

#define N 4096
#define FIN 512
#define HID 256
#define HEADS 4
#define DHEAD 256
#define FOUT 1024
#define TOPK 29
#define NW (N / 32)      // 128 mask words per column
#define CAP 2048         // per-row candidate capacity (mean ~20, 6+ sigma safe)
#define CAP2 512         // per-column source-list capacity (mean ~20)

// ---------------- fp32 tiled GEMM: C[M x Nn] = A[M x K] @ B[K x Nn] ----------
template <bool LRELU>
__global__ __launch_bounds__(256) void gemm64(const float* __restrict__ A,
                                              const float* __restrict__ B,
                                              float* __restrict__ C,
                                              int K, int Nn) {
  __shared__ float Ast[16][64];  // [k][m] (transposed stage -> float4 reads)
  __shared__ float Bs[16][64];   // [k][n]
  const int t = threadIdx.x;
  const int bm = blockIdx.x * 64, bn = blockIdx.y * 64;
  const int tx = t & 15, ty = t >> 4;  // 16x16 threads, 4x4 outputs each
  float acc[4][4] = {};
  for (int k0 = 0; k0 < K; k0 += 16) {
    {  // A tile 64 rows x 16 k
      const int m = t >> 2, kq = (t & 3) << 2;
      const float4 a4 = *reinterpret_cast<const float4*>(
          &A[(size_t)(bm + m) * K + k0 + kq]);
      Ast[kq + 0][m] = a4.x; Ast[kq + 1][m] = a4.y;
      Ast[kq + 2][m] = a4.z; Ast[kq + 3][m] = a4.w;
    }
    {  // B tile 16 k x 64 n
      const int kk = t >> 4, nq = (t & 15) << 2;
      *reinterpret_cast<float4*>(&Bs[kk][nq]) = *reinterpret_cast<const float4*>(
          &B[(size_t)(k0 + kk) * Nn + bn + nq]);
    }
    __syncthreads();
#pragma unroll
    for (int kk = 0; kk < 16; ++kk) {
      const float4 av = *reinterpret_cast<const float4*>(&Ast[kk][ty * 4]);
      const float4 bv = *reinterpret_cast<const float4*>(&Bs[kk][tx * 4]);
      const float a[4] = {av.x, av.y, av.z, av.w};
      const float b[4] = {bv.x, bv.y, bv.z, bv.w};
#pragma unroll
      for (int i = 0; i < 4; ++i)
#pragma unroll
        for (int j = 0; j < 4; ++j) acc[i][j] = fmaf(a[i], b[j], acc[i][j]);
    }
    __syncthreads();
  }
#pragma unroll
  for (int i = 0; i < 4; ++i)
#pragma unroll
    for (int j = 0; j < 4; ++j) {
      float v = acc[i][j];
      if (LRELU) v = v >= 0.f ? v : 0.01f * v;
      C[(size_t)(bm + ty * 4 + i) * Nn + bn + tx * 4 + j] = v;
    }
}

// ---------------- el/er: per-node per-head dots with attn vectors ------------
__global__ __launch_bounds__(256) void elr_kernel(const float* __restrict__ feat,
                                                  const float* __restrict__ attn_l,
                                                  const float* __restrict__ attn_r,
                                                  float* __restrict__ el,
                                                  float* __restrict__ er) {
  const int n = blockIdx.x;
  const int h = threadIdx.x >> 6, lane = threadIdx.x & 63;
  const float4 v = *reinterpret_cast<const float4*>(
      &feat[(size_t)n * FOUT + h * DHEAD + lane * 4]);
  const float4 al = *reinterpret_cast<const float4*>(&attn_l[h * DHEAD + lane * 4]);
  const float4 ar = *reinterpret_cast<const float4*>(&attn_r[h * DHEAD + lane * 4]);
  float sl = v.x * al.x + v.y * al.y + v.z * al.z + v.w * al.w;
  float sr = v.x * ar.x + v.y * ar.y + v.z * ar.z + v.w * ar.w;
  for (int off = 32; off; off >>= 1) {
    sl += __shfl_xor(sl, off);
    sr += __shfl_xor(sr, off);
  }
  if (lane == 0) {
    el[n * HEADS + h] = sl;
    er[n * HEADS + h] = sr;
  }
}

// ---------------- per-row top-29 positive selection -> transposed bitmask ----
__global__ __launch_bounds__(256) void topk_kernel(const float* __restrict__ simlar,
                                                   const float* __restrict__ adj,
                                                   unsigned int* __restrict__ maskT) {
  __shared__ float cv[CAP];
  __shared__ int cd[CAP];
  __shared__ int cnt;
  const int s = blockIdx.x, t = threadIdx.x;
  if (t == 0) cnt = 0;
  __syncthreads();
  const float4* sim4 = reinterpret_cast<const float4*>(simlar + (size_t)s * N);
  const float4* adj4 = reinterpret_cast<const float4*>(adj + (size_t)s * N);
  for (int i = t; i < N / 4; i += 256) {
    const float4 sv = sim4[i];
    const float4 av = adj4[i];
    const float ss[4] = {sv.x, sv.y, sv.z, sv.w};
    const float aa[4] = {av.x, av.y, av.z, av.w};
#pragma unroll
    for (int c = 0; c < 4; ++c) {
      if (aa[c] > 0.f && ss[c] > 0.f) {
        const int p = atomicAdd(&cnt, 1);
        if (p < CAP) { cv[p] = ss[c]; cd[p] = i * 4 + c; }
      }
    }
  }
  __syncthreads();
  const int C = min(cnt, CAP);
  const unsigned int bit = 1u << (s & 31);
  const int word = s >> 5;
  for (int i = t; i < C; i += 256) {
    const float v = cv[i];
    int g = 0;
    for (int j = 0; j < C; ++j) g += (cv[j] > v);
    if (g < TOPK) atomicOr(&maskT[(size_t)cd[i] * NW + word], bit);
  }
}

// ---------------- per-column softmax + weighted feature gather ---------------
__global__ __launch_bounds__(256) void agg_kernel(const unsigned int* __restrict__ maskT,
                                                  const float* __restrict__ el,
                                                  const float* __restrict__ er,
                                                  const float* __restrict__ feat,
                                                  const float* __restrict__ bias,
                                                  float* __restrict__ out) {
  __shared__ unsigned int words[NW];
  __shared__ int offs[NW + 1];
  __shared__ int slist[CAP2];
  __shared__ float pbuf[HEADS][CAP2];
  const int d = blockIdx.x, t = threadIdx.x;
  if (t < NW) words[t] = maskT[(size_t)d * NW + t];
  __syncthreads();
  if (t == 0) {
    int run = 0;
    for (int w = 0; w < NW; ++w) { offs[w] = run; run += __popc(words[w]); }
    offs[NW] = run;
  }
  __syncthreads();
  const int cnt = min(offs[NW], CAP2);
  if (t < NW) {
    unsigned int w = words[t];
    int pos = offs[t];
    while (w) {
      const int b = __ffs(w) - 1;
      w &= w - 1;
      if (pos < CAP2) slist[pos] = t * 32 + b;
      ++pos;
    }
  }
  __syncthreads();
  const int h = t >> 6, lane = t & 63;
  const float er_dh = er[d * HEADS + h];
  // pass A: running max of e over sources
  float m = -INFINITY;
  for (int i = lane; i < cnt; i += 64) {
    float e = el[slist[i] * HEADS + h] + er_dh;
    e = e >= 0.f ? e : 0.2f * e;
    m = fmaxf(m, e);
  }
  for (int off = 32; off; off >>= 1) m = fmaxf(m, __shfl_xor(m, off));
  // pass B: exp weights + denom
  float dsum = 0.f;
  for (int i = lane; i < cnt; i += 64) {
    float e = el[slist[i] * HEADS + h] + er_dh;
    e = e >= 0.f ? e : 0.2f * e;
    const float p = __expf(e - m);
    pbuf[h][i] = p;
    dsum += p;
  }
  for (int off = 32; off; off >>= 1) dsum += __shfl_xor(dsum, off);
  __syncthreads();
  // pass C: weighted gather of feat rows
  float4 acc = {0.f, 0.f, 0.f, 0.f};
  for (int i = 0; i < cnt; ++i) {
    const float p = pbuf[h][i];
    const float4 v = *reinterpret_cast<const float4*>(
        &feat[(size_t)slist[i] * FOUT + h * DHEAD + lane * 4]);
    acc.x = fmaf(p, v.x, acc.x);
    acc.y = fmaf(p, v.y, acc.y);
    acc.z = fmaf(p, v.z, acc.z);
    acc.w = fmaf(p, v.w, acc.w);
  }
  const float inv = cnt > 0 ? 1.f / dsum : 0.f;
  const float4 b4 = *reinterpret_cast<const float4*>(&bias[h * DHEAD + lane * 4]);
  float4 o;
  const float rx = acc.x * inv + b4.x;
  const float ry = acc.y * inv + b4.y;
  const float rz = acc.z * inv + b4.z;
  const float rw = acc.w * inv + b4.w;
  o.x = rx > 0.f ? rx : expm1f(rx);
  o.y = ry > 0.f ? ry : expm1f(ry);
  o.z = rz > 0.f ? rz : expm1f(rz);
  o.w = rw > 0.f ? rw : expm1f(rw);
  *reinterpret_cast<float4*>(&out[(size_t)d * FOUT + h * DHEAD + lane * 4]) = o;
}

extern "C" void kernel_launch(void* const* d_in, const int* in_sizes, int n_in,
                              void* d_out, int out_size, void* d_ws, size_t ws_size,
                              hipStream_t stream) {
  const float* h        = (const float*)d_in[0];
  const float* simlar   = (const float*)d_in[1];
  const float* adj      = (const float*)d_in[2];
  const float* W_trans  = (const float*)d_in[3];
  const float* gat_W    = (const float*)d_in[4];
  const float* attn_l   = (const float*)d_in[5];
  const float* attn_r   = (const float*)d_in[6];
  const float* gat_bias = (const float*)d_in[7];
  // sem_W1 / sem_b1 / sem_W2 unused: beta = softmax over a singleton axis == 1,
  // so out == sem exactly.
  float* out = (float*)d_out;

  char* ws = (char*)d_ws;
  float* x            = (float*)(ws);                         // 4 MB
  float* feat         = (float*)(ws + (4 << 20));             // 16 MB
  float* el           = (float*)(ws + (20 << 20));            // 64 KB
  float* er           = (float*)(ws + (20 << 20) + 65536);    // 64 KB
  unsigned int* maskT = (unsigned int*)(ws + (21 << 20));     // 2 MB

  hipMemsetAsync(maskT, 0, (size_t)N * NW * sizeof(unsigned int), stream);

  gemm64<true><<<dim3(N / 64, HID / 64), 256, 0, stream>>>(h, W_trans, x, FIN, HID);
  gemm64<false><<<dim3(N / 64, FOUT / 64), 256, 0, stream>>>(x, gat_W, feat, HID, FOUT);
  elr_kernel<<<N, 256, 0, stream>>>(feat, attn_l, attn_r, el, er);
  topk_kernel<<<N, 256, 0, stream>>>(simlar, adj, maskT);
  agg_kernel<<<N, 256, 0, stream>>>(maskT, el, er, feat, gat_bias, out);
}

// Round 3
// 120.685 us; speedup vs baseline: 1.2078x; 1.2078x over previous
//
#include <hip/hip_runtime.h>
#include <hip/hip_bf16.h>
#include <math.h>

#define N 4096
#define FIN 512
#define HID 256
#define HEADS 4
#define DHEAD 256
#define FOUT 1024
#define TOPK 29
#define NW (N / 32)      // 128 mask words per column
#define CAP 64           // per-row candidate capacity (mean ~20.5, sd 4.5 -> 9+ sigma)
#define CAP2 128         // per-column source-list capacity

typedef __attribute__((ext_vector_type(8))) short short8;
typedef __attribute__((ext_vector_type(4))) float f32x4;
typedef __hip_bfloat16 bf16;

// ---------------- fp32 -> bf16 elementwise convert (vectorized) --------------
__global__ __launch_bounds__(256) void conv_bf16(const float* __restrict__ src,
                                                 bf16* __restrict__ dst, int n4) {
  int i = blockIdx.x * 256 + threadIdx.x;
  const int stride = gridDim.x * 256;
  for (; i < n4; i += stride) {
    const float4 v = reinterpret_cast<const float4*>(src)[i];
    bf16 tmp[4];
    tmp[0] = __float2bfloat16(v.x);
    tmp[1] = __float2bfloat16(v.y);
    tmp[2] = __float2bfloat16(v.z);
    tmp[3] = __float2bfloat16(v.w);
    *reinterpret_cast<ushort4*>(&dst[(size_t)i * 4]) = *reinterpret_cast<ushort4*>(tmp);
  }
}

// ---------------- fp32 [K x Nn] -> bf16 transposed [Nn x K] ------------------
__global__ __launch_bounds__(256) void convT_bf16(const float* __restrict__ src,
                                                  bf16* __restrict__ dst, int K, int Nn) {
  const int idx = blockIdx.x * 256 + threadIdx.x;
  if (idx >= K * Nn) return;
  const int nrow = idx / K, k = idx % K;
  dst[idx] = __float2bfloat16(src[(size_t)k * Nn + nrow]);
}

// ---------------- bf16 MFMA GEMM: C[M x Nn] = A[M x K] @ Bt[Nn x K]^T --------
// BM=128, BN=64, BK=32, 256 threads (4 waves), each wave 32x64 via 2x4 16x16 frags.
// OUTMODE 0: fp32 out; 1: lrelu(0.01) + bf16 out.
template <int OUTMODE>
__global__ __launch_bounds__(256) void gemm_mfma(const bf16* __restrict__ A,
                                                 const bf16* __restrict__ Bt,
                                                 float* __restrict__ Cf,
                                                 bf16* __restrict__ Cb,
                                                 int M, int Nn, int K) {
  __shared__ bf16 As[128][40];  // +8 pad: 80B row stride, 16B-aligned, 2-way max
  __shared__ bf16 Bs[64][40];
  const int t = threadIdx.x;
  const int bm = blockIdx.x * 128, bn = blockIdx.y * 64;
  const int w = t >> 6, lane = t & 63, r = lane & 15, g = lane >> 4;
  f32x4 acc[2][4] = {};
  for (int k0 = 0; k0 < K; k0 += 32) {
    {  // stage A: 128 rows x 32 k = 512 x 16B chunks, 2 per thread
      int c = t;
#pragma unroll
      for (int rep = 0; rep < 2; ++rep, c += 256) {
        const int m = c >> 2, kq = (c & 3) * 8;
        const int4 av = *reinterpret_cast<const int4*>(&A[(size_t)(bm + m) * K + k0 + kq]);
        *reinterpret_cast<int4*>(&As[m][kq]) = av;
      }
    }
    {  // stage Bt: 64 rows x 32 k = 256 x 16B chunks, 1 per thread
      const int m = t >> 2, kq = (t & 3) * 8;
      const int4 bv = *reinterpret_cast<const int4*>(&Bt[(size_t)(bn + m) * K + k0 + kq]);
      *reinterpret_cast<int4*>(&Bs[m][kq]) = bv;
    }
    __syncthreads();
    short8 a0 = *reinterpret_cast<short8*>(&As[w * 32 + r][g * 8]);
    short8 a1 = *reinterpret_cast<short8*>(&As[w * 32 + 16 + r][g * 8]);
#pragma unroll
    for (int j = 0; j < 4; ++j) {
      short8 b = *reinterpret_cast<short8*>(&Bs[j * 16 + r][g * 8]);
      acc[0][j] = __builtin_amdgcn_mfma_f32_16x16x32_bf16(a0, b, acc[0][j], 0, 0, 0);
      acc[1][j] = __builtin_amdgcn_mfma_f32_16x16x32_bf16(a1, b, acc[1][j], 0, 0, 0);
    }
    __syncthreads();
  }
#pragma unroll
  for (int i = 0; i < 2; ++i)
#pragma unroll
    for (int j = 0; j < 4; ++j)
#pragma unroll
      for (int q = 0; q < 4; ++q) {
        const int row = bm + w * 32 + i * 16 + g * 4 + q;
        const int col = bn + j * 16 + r;
        float v = acc[i][j][q];
        if (OUTMODE == 1) {
          v = v >= 0.f ? v : 0.01f * v;
          Cb[(size_t)row * Nn + col] = __float2bfloat16(v);
        } else {
          Cf[(size_t)row * Nn + col] = v;
        }
      }
}

// ---------------- el/er: per-node per-head dots with attn vectors ------------
__global__ __launch_bounds__(256) void elr_kernel(const float* __restrict__ feat,
                                                  const float* __restrict__ attn_l,
                                                  const float* __restrict__ attn_r,
                                                  float* __restrict__ el,
                                                  float* __restrict__ er) {
  const int n = blockIdx.x;
  const int h = threadIdx.x >> 6, lane = threadIdx.x & 63;
  const float4 v = *reinterpret_cast<const float4*>(
      &feat[(size_t)n * FOUT + h * DHEAD + lane * 4]);
  const float4 al = *reinterpret_cast<const float4*>(&attn_l[h * DHEAD + lane * 4]);
  const float4 ar = *reinterpret_cast<const float4*>(&attn_r[h * DHEAD + lane * 4]);
  float sl = v.x * al.x + v.y * al.y + v.z * al.z + v.w * al.w;
  float sr = v.x * ar.x + v.y * ar.y + v.z * ar.z + v.w * ar.w;
  for (int off = 32; off; off >>= 1) {
    sl += __shfl_xor(sl, off);
    sr += __shfl_xor(sr, off);
  }
  if (lane == 0) {
    el[n * HEADS + h] = sl;
    er[n * HEADS + h] = sr;
  }
}

// ---------------- stream adj (skip simlar where adj==0), compact candidates --
__global__ __launch_bounds__(256) void stream_kernel(const float* __restrict__ adj,
                                                     const float* __restrict__ simlar,
                                                     int* __restrict__ rowcnt,
                                                     float* __restrict__ rowval,
                                                     int* __restrict__ rowidx) {
  int i = blockIdx.x * 256 + threadIdx.x;
  const int stride = gridDim.x * 256;
  const float4* adj4 = reinterpret_cast<const float4*>(adj);
  const float4* sim4 = reinterpret_cast<const float4*>(simlar);
  for (; i < N * N / 4; i += stride) {
    const float4 a4 = adj4[i];
    if (a4.x > 0.f || a4.y > 0.f || a4.z > 0.f || a4.w > 0.f) {
      const float4 s4 = sim4[i];
      const int s = i >> 10;  // N/4 = 1024 float4 per row
      const float aa[4] = {a4.x, a4.y, a4.z, a4.w};
      const float ss[4] = {s4.x, s4.y, s4.z, s4.w};
#pragma unroll
      for (int c = 0; c < 4; ++c) {
        if (aa[c] > 0.f && ss[c] > 0.f) {
          const int p = atomicAdd(&rowcnt[s], 1);
          if (p < CAP) {
            rowval[s * CAP + p] = ss[c];
            rowidx[s * CAP + p] = (i & 1023) * 4 + c;
          }
        }
      }
    }
  }
}

// ---------------- per-row top-29 rank select -> transposed bitmask -----------
__global__ __launch_bounds__(64) void select_kernel(const int* __restrict__ rowcnt,
                                                    const float* __restrict__ rowval,
                                                    const int* __restrict__ rowidx,
                                                    unsigned int* __restrict__ maskT) {
  const int s = blockIdx.x, t = threadIdx.x;
  __shared__ float v[CAP];
  const int C = min(rowcnt[s], CAP);
  if (t < C) v[t] = rowval[s * CAP + t];
  __syncthreads();
  if (t < C) {
    const float x = v[t];
    int g = 0;
    for (int j = 0; j < C; ++j) g += (v[j] > x);
    if (g < TOPK) {
      const int d = rowidx[s * CAP + t];
      atomicOr(&maskT[(size_t)d * NW + (s >> 5)], 1u << (s & 31));
    }
  }
}

// ---------------- per-column softmax + weighted feature gather ---------------
__global__ __launch_bounds__(256) void agg_kernel(const unsigned int* __restrict__ maskT,
                                                  const float* __restrict__ el,
                                                  const float* __restrict__ er,
                                                  const float* __restrict__ feat,
                                                  const float* __restrict__ bias,
                                                  float* __restrict__ out) {
  __shared__ unsigned int words[NW];
  __shared__ int tmp[CAP2];
  __shared__ int slist[CAP2];
  __shared__ int cnt;
  __shared__ float pbuf[HEADS][CAP2];
  const int d = blockIdx.x, t = threadIdx.x;
  if (t == 0) cnt = 0;
  if (t < NW) words[t] = maskT[(size_t)d * NW + t];
  __syncthreads();
  if (t < NW) {
    unsigned int wd = words[t];
    while (wd) {
      const int b = __ffs(wd) - 1;
      wd &= wd - 1;
      const int p = atomicAdd(&cnt, 1);
      if (p < CAP2) tmp[p] = t * 32 + b;
    }
  }
  __syncthreads();
  const int C = min(cnt, CAP2);
  // rank-sort into ascending source order (deterministic regardless of atomics)
  for (int i = t; i < C; i += 256) {
    const int v = tmp[i];
    int g = 0;
    for (int j = 0; j < C; ++j) g += (tmp[j] < v);
    slist[g] = v;
  }
  __syncthreads();
  const int h = t >> 6, lane = t & 63;
  const float er_dh = er[d * HEADS + h];
  // pass A: max of e over sources
  float m = -INFINITY;
  for (int i = lane; i < C; i += 64) {
    float e = el[slist[i] * HEADS + h] + er_dh;
    e = e >= 0.f ? e : 0.2f * e;
    m = fmaxf(m, e);
  }
  for (int off = 32; off; off >>= 1) m = fmaxf(m, __shfl_xor(m, off));
  // pass B: exp weights + denom
  float dsum = 0.f;
  for (int i = lane; i < C; i += 64) {
    float e = el[slist[i] * HEADS + h] + er_dh;
    e = e >= 0.f ? e : 0.2f * e;
    const float p = __expf(e - m);
    pbuf[h][i] = p;
    dsum += p;
  }
  for (int off = 32; off; off >>= 1) dsum += __shfl_xor(dsum, off);
  __syncthreads();
  // pass C: weighted gather of feat rows
  float4 acc = {0.f, 0.f, 0.f, 0.f};
  for (int i = 0; i < C; ++i) {
    const float p = pbuf[h][i];
    const float4 v = *reinterpret_cast<const float4*>(
        &feat[(size_t)slist[i] * FOUT + h * DHEAD + lane * 4]);
    acc.x = fmaf(p, v.x, acc.x);
    acc.y = fmaf(p, v.y, acc.y);
    acc.z = fmaf(p, v.z, acc.z);
    acc.w = fmaf(p, v.w, acc.w);
  }
  const float inv = C > 0 ? 1.f / dsum : 0.f;
  const float4 b4 = *reinterpret_cast<const float4*>(&bias[h * DHEAD + lane * 4]);
  const float rx = acc.x * inv + b4.x;
  const float ry = acc.y * inv + b4.y;
  const float rz = acc.z * inv + b4.z;
  const float rw = acc.w * inv + b4.w;
  float4 o;
  o.x = rx > 0.f ? rx : expm1f(rx);
  o.y = ry > 0.f ? ry : expm1f(ry);
  o.z = rz > 0.f ? rz : expm1f(rz);
  o.w = rw > 0.f ? rw : expm1f(rw);
  *reinterpret_cast<float4*>(&out[(size_t)d * FOUT + h * DHEAD + lane * 4]) = o;
}

extern "C" void kernel_launch(void* const* d_in, const int* in_sizes, int n_in,
                              void* d_out, int out_size, void* d_ws, size_t ws_size,
                              hipStream_t stream) {
  const float* h        = (const float*)d_in[0];
  const float* simlar   = (const float*)d_in[1];
  const float* adj      = (const float*)d_in[2];
  const float* W_trans  = (const float*)d_in[3];
  const float* gat_W    = (const float*)d_in[4];
  const float* attn_l   = (const float*)d_in[5];
  const float* attn_r   = (const float*)d_in[6];
  const float* gat_bias = (const float*)d_in[7];
  // sem_W1 / sem_b1 / sem_W2 unused: beta = softmax over singleton == 1 -> out == sem.
  float* out = (float*)d_out;

  char* ws = (char*)d_ws;
  const size_t MB = 1 << 20;
  bf16* hb            = (bf16*)(ws);                    // 4 MB   (N x FIN)
  bf16* Wtb           = (bf16*)(ws + 4 * MB);           // 256 KB (HID x FIN)
  bf16* gWtb          = (bf16*)(ws + 4 * MB + 512 * 1024);  // 512 KB (FOUT x HID)
  bf16* xb            = (bf16*)(ws + 5 * MB);           // 2 MB   (N x HID)
  float* el           = (float*)(ws + 7 * MB);          // 64 KB
  float* er           = (float*)(ws + 7 * MB + 65536);  // 64 KB
  float* feat         = (float*)(ws + 8 * MB);          // 16 MB  (N x FOUT)
  unsigned int* maskT = (unsigned int*)(ws + 24 * MB);  // 2 MB
  int* rowcnt         = (int*)(ws + 26 * MB);           // 16 KB
  float* rowval       = (float*)(ws + 26 * MB + 65536); // 1 MB
  int* rowidx         = (int*)(ws + 27 * MB + 65536);   // 1 MB

  hipMemsetAsync(maskT, 0, (size_t)N * NW * sizeof(unsigned int), stream);
  hipMemsetAsync(rowcnt, 0, (size_t)N * sizeof(int), stream);

  // heaviest BW kernel first
  stream_kernel<<<2048, 256, 0, stream>>>(adj, simlar, rowcnt, rowval, rowidx);
  select_kernel<<<N, 64, 0, stream>>>(rowcnt, rowval, rowidx, maskT);

  conv_bf16<<<2048, 256, 0, stream>>>(h, hb, N * FIN / 4);
  convT_bf16<<<(FIN * HID + 255) / 256, 256, 0, stream>>>(W_trans, Wtb, FIN, HID);
  convT_bf16<<<(HID * FOUT + 255) / 256, 256, 0, stream>>>(gat_W, gWtb, HID, FOUT);

  gemm_mfma<1><<<dim3(N / 128, HID / 64), 256, 0, stream>>>(hb, Wtb, nullptr, xb, N, HID, FIN);
  gemm_mfma<0><<<dim3(N / 128, FOUT / 64), 256, 0, stream>>>(xb, gWtb, feat, nullptr, N, FOUT, HID);

  elr_kernel<<<N, 256, 0, stream>>>(feat, attn_l, attn_r, el, er);
  agg_kernel<<<N, 256, 0, stream>>>(maskT, el, er, feat, gat_bias, out);
}

// Round 4
// 101.161 us; speedup vs baseline: 1.4410x; 1.1930x over previous
//
#include <hip/hip_runtime.h>
#include <hip/hip_bf16.h>
#include <math.h>

#define N 4096
#define FIN 512
#define HID 256
#define HEADS 4
#define DHEAD 256
#define FOUT 1024
#define TOPK 29
#define NW (N / 32)      // 128 mask words per column
#define CAP 64           // per-row candidate capacity (mean ~20.5, sd 4.5 -> 9+ sigma)
#define CAP2 128         // per-column source-list capacity

typedef __attribute__((ext_vector_type(8))) short short8;
typedef __attribute__((ext_vector_type(4))) float f32x4;
typedef __hip_bfloat16 bf16;

__device__ __forceinline__ float bflo(unsigned int u) {
  return __uint_as_float(u << 16);
}
__device__ __forceinline__ float bfhi(unsigned int u) {
  return __uint_as_float(u & 0xffff0000u);
}

// ---------------- fp32 -> bf16 elementwise convert (vectorized) --------------
__global__ __launch_bounds__(256) void conv_bf16(const float* __restrict__ src,
                                                 bf16* __restrict__ dst, int n4) {
  int i = blockIdx.x * 256 + threadIdx.x;
  const int stride = gridDim.x * 256;
  for (; i < n4; i += stride) {
    const float4 v = reinterpret_cast<const float4*>(src)[i];
    bf16 tmp[4];
    tmp[0] = __float2bfloat16(v.x);
    tmp[1] = __float2bfloat16(v.y);
    tmp[2] = __float2bfloat16(v.z);
    tmp[3] = __float2bfloat16(v.w);
    *reinterpret_cast<ushort4*>(&dst[(size_t)i * 4]) = *reinterpret_cast<ushort4*>(tmp);
  }
}

// ---------------- fp32 [K x Nn] -> bf16 transposed [Nn x K] ------------------
__global__ __launch_bounds__(256) void convT_bf16(const float* __restrict__ src,
                                                  bf16* __restrict__ dst, int K, int Nn) {
  const int idx = blockIdx.x * 256 + threadIdx.x;
  if (idx >= K * Nn) return;
  const int nrow = idx / K, k = idx % K;
  dst[idx] = __float2bfloat16(src[(size_t)k * Nn + nrow]);
}

// ---------------- bf16 MFMA GEMM: C[M x Nn] = A[M x K] @ Bt[Nn x K]^T --------
// BM=128, BN=64, BK=32, 256 threads (4 waves), each wave 32x64 via 2x4 16x16 frags.
// OUTMODE 1: lrelu(0.01) + bf16 out; 2: plain bf16 out.
template <int OUTMODE>
__global__ __launch_bounds__(256) void gemm_mfma(const bf16* __restrict__ A,
                                                 const bf16* __restrict__ Bt,
                                                 bf16* __restrict__ Cb,
                                                 int M, int Nn, int K) {
  __shared__ bf16 As[128][40];  // +8 pad: 80B row stride, 16B-aligned, 2-way max
  __shared__ bf16 Bs[64][40];
  const int t = threadIdx.x;
  const int bm = blockIdx.x * 128, bn = blockIdx.y * 64;
  const int w = t >> 6, lane = t & 63, r = lane & 15, g = lane >> 4;
  f32x4 acc[2][4] = {};
  for (int k0 = 0; k0 < K; k0 += 32) {
    {  // stage A: 128 rows x 32 k = 512 x 16B chunks, 2 per thread
      int c = t;
#pragma unroll
      for (int rep = 0; rep < 2; ++rep, c += 256) {
        const int m = c >> 2, kq = (c & 3) * 8;
        const int4 av = *reinterpret_cast<const int4*>(&A[(size_t)(bm + m) * K + k0 + kq]);
        *reinterpret_cast<int4*>(&As[m][kq]) = av;
      }
    }
    {  // stage Bt: 64 rows x 32 k = 256 x 16B chunks, 1 per thread
      const int m = t >> 2, kq = (t & 3) * 8;
      const int4 bv = *reinterpret_cast<const int4*>(&Bt[(size_t)(bn + m) * K + k0 + kq]);
      *reinterpret_cast<int4*>(&Bs[m][kq]) = bv;
    }
    __syncthreads();
    short8 a0 = *reinterpret_cast<short8*>(&As[w * 32 + r][g * 8]);
    short8 a1 = *reinterpret_cast<short8*>(&As[w * 32 + 16 + r][g * 8]);
#pragma unroll
    for (int j = 0; j < 4; ++j) {
      short8 b = *reinterpret_cast<short8*>(&Bs[j * 16 + r][g * 8]);
      acc[0][j] = __builtin_amdgcn_mfma_f32_16x16x32_bf16(a0, b, acc[0][j], 0, 0, 0);
      acc[1][j] = __builtin_amdgcn_mfma_f32_16x16x32_bf16(a1, b, acc[1][j], 0, 0, 0);
    }
    __syncthreads();
  }
#pragma unroll
  for (int i = 0; i < 2; ++i)
#pragma unroll
    for (int j = 0; j < 4; ++j)
#pragma unroll
      for (int q = 0; q < 4; ++q) {
        const int row = bm + w * 32 + i * 16 + g * 4 + q;
        const int col = bn + j * 16 + r;
        float v = acc[i][j][q];
        if (OUTMODE == 1) v = v >= 0.f ? v : 0.01f * v;
        Cb[(size_t)row * Nn + col] = __float2bfloat16(v);
      }
}

// ---------------- el/er: per-node per-head dots with attn vectors ------------
__global__ __launch_bounds__(256) void elr_kernel(const bf16* __restrict__ featb,
                                                  const float* __restrict__ attn_l,
                                                  const float* __restrict__ attn_r,
                                                  float* __restrict__ el,
                                                  float* __restrict__ er) {
  const int n = blockIdx.x;
  const int h = threadIdx.x >> 6, lane = threadIdx.x & 63;
  const uint2 v2 = *reinterpret_cast<const uint2*>(
      &featb[(size_t)n * FOUT + h * DHEAD + lane * 4]);
  const float f0 = bflo(v2.x), f1 = bfhi(v2.x), f2 = bflo(v2.y), f3 = bfhi(v2.y);
  const float4 al = *reinterpret_cast<const float4*>(&attn_l[h * DHEAD + lane * 4]);
  const float4 ar = *reinterpret_cast<const float4*>(&attn_r[h * DHEAD + lane * 4]);
  float sl = f0 * al.x + f1 * al.y + f2 * al.z + f3 * al.w;
  float sr = f0 * ar.x + f1 * ar.y + f2 * ar.z + f3 * ar.w;
  for (int off = 32; off; off >>= 1) {
    sl += __shfl_xor(sl, off);
    sr += __shfl_xor(sr, off);
  }
  if (lane == 0) {
    el[n * HEADS + h] = sl;
    er[n * HEADS + h] = sr;
  }
}

// ---------------- stream adj (skip simlar where adj==0), compact candidates --
__global__ __launch_bounds__(256) void stream_kernel(const float* __restrict__ adj,
                                                     const float* __restrict__ simlar,
                                                     int* __restrict__ rowcnt,
                                                     float* __restrict__ rowval,
                                                     int* __restrict__ rowidx) {
  int i = blockIdx.x * 256 + threadIdx.x;
  const int stride = gridDim.x * 256;
  const float4* adj4 = reinterpret_cast<const float4*>(adj);
  const float4* sim4 = reinterpret_cast<const float4*>(simlar);
  for (; i < N * N / 4; i += stride) {
    const float4 a4 = adj4[i];
    if (a4.x > 0.f || a4.y > 0.f || a4.z > 0.f || a4.w > 0.f) {
      const float4 s4 = sim4[i];
      const int s = i >> 10;  // N/4 = 1024 float4 per row
      const float aa[4] = {a4.x, a4.y, a4.z, a4.w};
      const float ss[4] = {s4.x, s4.y, s4.z, s4.w};
#pragma unroll
      for (int c = 0; c < 4; ++c) {
        if (aa[c] > 0.f && ss[c] > 0.f) {
          const int p = atomicAdd(&rowcnt[s], 1);
          if (p < CAP) {
            rowval[s * CAP + p] = ss[c];
            rowidx[s * CAP + p] = (i & 1023) * 4 + c;
          }
        }
      }
    }
  }
}

// ---------------- per-row top-29 rank select -> transposed bitmask -----------
__global__ __launch_bounds__(64) void select_kernel(const int* __restrict__ rowcnt,
                                                    const float* __restrict__ rowval,
                                                    const int* __restrict__ rowidx,
                                                    unsigned int* __restrict__ maskT) {
  const int s = blockIdx.x, t = threadIdx.x;
  __shared__ float v[CAP];
  const int C = min(rowcnt[s], CAP);
  if (t < C) v[t] = rowval[s * CAP + t];
  __syncthreads();
  if (t < C) {
    const float x = v[t];
    int g = 0;
    for (int j = 0; j < C; ++j) g += (v[j] > x);
    if (g < TOPK) {
      const int d = rowidx[s * CAP + t];
      atomicOr(&maskT[(size_t)d * NW + (s >> 5)], 1u << (s & 31));
    }
  }
}

// ---------------- per-column softmax + weighted bf16 feature gather ----------
// 2 destination columns per block; 128 lanes per column, 8 dims per lane (16B).
__global__ __launch_bounds__(256) void agg_kernel(const unsigned int* __restrict__ maskT,
                                                  const float* __restrict__ el,
                                                  const float* __restrict__ er,
                                                  const bf16* __restrict__ featb,
                                                  const float* __restrict__ bias,
                                                  float* __restrict__ out) {
  __shared__ unsigned int words[2][NW];
  __shared__ int tmp[2][CAP2];
  __shared__ int slist[2][CAP2];
  __shared__ int cnt[2];
  __shared__ float pbuf[2][HEADS][CAP2];
  const int t = threadIdx.x;
  const int grp = t >> 7;   // which of the 2 columns
  const int g = t & 127;    // lane within column group
  const int d = blockIdx.x * 2 + grp;
  if (g == 0) cnt[grp] = 0;
  if (g < NW) words[grp][g] = maskT[(size_t)d * NW + g];
  __syncthreads();
  if (g < NW) {
    unsigned int wd = words[grp][g];
    while (wd) {
      const int b = __ffs(wd) - 1;
      wd &= wd - 1;
      const int p = atomicAdd(&cnt[grp], 1);
      if (p < CAP2) tmp[grp][p] = g * 32 + b;
    }
  }
  __syncthreads();
  const int C = min(cnt[grp], CAP2);
  // rank-sort into ascending source order (deterministic regardless of atomics)
  for (int i = g; i < C; i += 128) {
    const int v = tmp[grp][i];
    int rk = 0;
    for (int j = 0; j < C; ++j) rk += (tmp[grp][j] < v);
    slist[grp][rk] = v;
  }
  __syncthreads();
  const int h = g >> 5;      // 4 heads x 32 lanes (head = 256 dims = 32 x 8)
  const int hl = g & 31;
  const float er_dh = er[d * HEADS + h];
  // pass A: e values -> pbuf, running max (32-lane head group)
  float m = -INFINITY;
  for (int i = hl; i < C; i += 32) {
    float e = el[slist[grp][i] * HEADS + h] + er_dh;
    e = e >= 0.f ? e : 0.2f * e;
    pbuf[grp][h][i] = e;
    m = fmaxf(m, e);
  }
#pragma unroll
  for (int off = 16; off; off >>= 1) m = fmaxf(m, __shfl_xor(m, off));
  // pass B: exp in place (same lanes touch same entries), denom reduce
  float dsum = 0.f;
  for (int i = hl; i < C; i += 32) {
    const float p = __expf(pbuf[grp][h][i] - m);
    pbuf[grp][h][i] = p;
    dsum += p;
  }
#pragma unroll
  for (int off = 16; off; off >>= 1) dsum += __shfl_xor(dsum, off);
  __syncthreads();
  // pass C: weighted gather of bf16 feat rows (128 lanes x 16B = 2KB/row)
  float acc[8] = {};
  for (int i = 0; i < C; ++i) {
    const float p = pbuf[grp][h][i];
    const uint4 v = *reinterpret_cast<const uint4*>(
        &featb[(size_t)slist[grp][i] * FOUT + g * 8]);
    acc[0] = fmaf(p, bflo(v.x), acc[0]);
    acc[1] = fmaf(p, bfhi(v.x), acc[1]);
    acc[2] = fmaf(p, bflo(v.y), acc[2]);
    acc[3] = fmaf(p, bfhi(v.y), acc[3]);
    acc[4] = fmaf(p, bflo(v.z), acc[4]);
    acc[5] = fmaf(p, bfhi(v.z), acc[5]);
    acc[6] = fmaf(p, bflo(v.w), acc[6]);
    acc[7] = fmaf(p, bfhi(v.w), acc[7]);
  }
  const float inv = C > 0 ? 1.f / dsum : 0.f;
  float o[8];
#pragma unroll
  for (int k = 0; k < 8; ++k) {
    const float r = acc[k] * inv + bias[g * 8 + k];
    o[k] = r > 0.f ? r : expm1f(r);
  }
  float* op = &out[(size_t)d * FOUT + g * 8];
  *reinterpret_cast<float4*>(op) = make_float4(o[0], o[1], o[2], o[3]);
  *reinterpret_cast<float4*>(op + 4) = make_float4(o[4], o[5], o[6], o[7]);
}

extern "C" void kernel_launch(void* const* d_in, const int* in_sizes, int n_in,
                              void* d_out, int out_size, void* d_ws, size_t ws_size,
                              hipStream_t stream) {
  const float* h        = (const float*)d_in[0];
  const float* simlar   = (const float*)d_in[1];
  const float* adj      = (const float*)d_in[2];
  const float* W_trans  = (const float*)d_in[3];
  const float* gat_W    = (const float*)d_in[4];
  const float* attn_l   = (const float*)d_in[5];
  const float* attn_r   = (const float*)d_in[6];
  const float* gat_bias = (const float*)d_in[7];
  // sem_W1 / sem_b1 / sem_W2 unused: beta = softmax over singleton == 1 -> out == sem.
  float* out = (float*)d_out;

  char* ws = (char*)d_ws;
  const size_t MB = 1 << 20;
  bf16* hb            = (bf16*)(ws);                        // 4 MB   (N x FIN)
  bf16* Wtb           = (bf16*)(ws + 4 * MB);               // 256 KB (HID x FIN)
  bf16* gWtb          = (bf16*)(ws + 4 * MB + 512 * 1024);  // 512 KB (FOUT x HID)
  bf16* xb            = (bf16*)(ws + 5 * MB);               // 2 MB   (N x HID)
  float* el           = (float*)(ws + 7 * MB);              // 64 KB
  float* er           = (float*)(ws + 7 * MB + 65536);      // 64 KB
  bf16* featb         = (bf16*)(ws + 8 * MB);               // 8 MB   (N x FOUT bf16)
  unsigned int* maskT = (unsigned int*)(ws + 24 * MB);      // 2 MB
  int* rowcnt         = (int*)(ws + 26 * MB);               // 16 KB
  float* rowval       = (float*)(ws + 26 * MB + 65536);     // 1 MB
  int* rowidx         = (int*)(ws + 27 * MB + 65536);       // 1 MB

  hipMemsetAsync(maskT, 0, (size_t)N * NW * sizeof(unsigned int), stream);
  hipMemsetAsync(rowcnt, 0, (size_t)N * sizeof(int), stream);

  // heaviest BW kernel first
  stream_kernel<<<2048, 256, 0, stream>>>(adj, simlar, rowcnt, rowval, rowidx);
  select_kernel<<<N, 64, 0, stream>>>(rowcnt, rowval, rowidx, maskT);

  conv_bf16<<<2048, 256, 0, stream>>>(h, hb, N * FIN / 4);
  convT_bf16<<<(FIN * HID + 255) / 256, 256, 0, stream>>>(W_trans, Wtb, FIN, HID);
  convT_bf16<<<(HID * FOUT + 255) / 256, 256, 0, stream>>>(gat_W, gWtb, HID, FOUT);

  gemm_mfma<1><<<dim3(N / 128, HID / 64), 256, 0, stream>>>(hb, Wtb, xb, N, HID, FIN);
  gemm_mfma<2><<<dim3(N / 128, FOUT / 64), 256, 0, stream>>>(xb, gWtb, featb, N, FOUT, HID);

  elr_kernel<<<N, 256, 0, stream>>>(featb, attn_l, attn_r, el, er);
  agg_kernel<<<N / 2, 256, 0, stream>>>(maskT, el, er, featb, gat_bias, out);
}

// Round 5
// 92.795 us; speedup vs baseline: 1.5709x; 1.0902x over previous
//
#include <hip/hip_runtime.h>
#include <hip/hip_bf16.h>
#include <math.h>

#define N 4096
#define FIN 512
#define HID 256
#define HEADS 4
#define DHEAD 256
#define FOUT 1024
#define TOPK 29
#define CAP 64    // per-row candidate capacity (mean ~20.5, sd ~4.5)
#define CAPC 96   // per-column source capacity (in-degree mean ~20.4, sd ~4.5)

typedef __attribute__((ext_vector_type(8))) short short8;
typedef __attribute__((ext_vector_type(4))) float f32x4;
typedef __hip_bfloat16 bf16;

__device__ __forceinline__ float bflo(unsigned int u) {
  return __uint_as_float(u << 16);
}
__device__ __forceinline__ float bfhi(unsigned int u) {
  return __uint_as_float(u & 0xffff0000u);
}

// ---- fused prep: zero counters + h->bf16 + W_trans^T->bf16 + gat_W^T->bf16 --
__global__ __launch_bounds__(256) void prep_kernel(const float* __restrict__ h,
                                                   const float* __restrict__ W_trans,
                                                   const float* __restrict__ gat_W,
                                                   bf16* __restrict__ hb,
                                                   bf16* __restrict__ Wtb,
                                                   bf16* __restrict__ gWtb,
                                                   int* __restrict__ counters) {
  const int CZ = 2 * N;            // 8192 counter ints (rowcnt + colcnt)
  const int H4 = N * FIN / 4;      // 524288 float4 of h
  const int WT = HID * FIN;        // 131072 Wtb elements [HID][FIN]
  const int GT = FOUT * HID;       // 262144 gWtb elements [FOUT][HID]
  const int total = CZ + H4 + WT + GT;
  int i = blockIdx.x * 256 + threadIdx.x;
  const int stride = gridDim.x * 256;
  for (; i < total; i += stride) {
    if (i < CZ) {
      counters[i] = 0;
    } else if (i < CZ + H4) {
      const int j = i - CZ;
      const float4 v = reinterpret_cast<const float4*>(h)[j];
      bf16 tmp[4];
      tmp[0] = __float2bfloat16(v.x);
      tmp[1] = __float2bfloat16(v.y);
      tmp[2] = __float2bfloat16(v.z);
      tmp[3] = __float2bfloat16(v.w);
      *reinterpret_cast<ushort4*>(&hb[(size_t)j * 4]) = *reinterpret_cast<ushort4*>(tmp);
    } else if (i < CZ + H4 + WT) {
      const int j = i - CZ - H4;
      const int row = j >> 9, k = j & 511;  // [HID][FIN], FIN=512
      Wtb[j] = __float2bfloat16(W_trans[(size_t)k * HID + row]);
    } else {
      const int j = i - CZ - H4 - WT;
      const int row = j >> 8, k = j & 255;  // [FOUT][HID], HID=256
      gWtb[j] = __float2bfloat16(gat_W[(size_t)k * FOUT + row]);
    }
  }
}

// ---------------- bf16 MFMA GEMM: C[M x Nn] = A[M x K] @ Bt[Nn x K]^T --------
// BM=64, BN=64, BK=32, 256 threads (4 waves); wave w owns rows [w*16, w*16+16),
// 1x4 16x16x32 frags. OUTMODE 1: lrelu(0.01)+bf16 out; 2: plain bf16 out.
template <int OUTMODE>
__global__ __launch_bounds__(256) void gemm_mfma(const bf16* __restrict__ A,
                                                 const bf16* __restrict__ Bt,
                                                 bf16* __restrict__ Cb,
                                                 int M, int Nn, int K) {
  __shared__ bf16 As[64][40];  // +8 pad (80B stride)
  __shared__ bf16 Bs[64][40];
  const int t = threadIdx.x;
  const int bm = blockIdx.x * 64, bn = blockIdx.y * 64;
  const int w = t >> 6, lane = t & 63, r = lane & 15, g = lane >> 4;
  const int m = t >> 2, kq = (t & 3) * 8;  // staging coords: 64 rows x 4 chunks
  f32x4 acc[4] = {};
  for (int k0 = 0; k0 < K; k0 += 32) {
    *reinterpret_cast<int4*>(&As[m][kq]) =
        *reinterpret_cast<const int4*>(&A[(size_t)(bm + m) * K + k0 + kq]);
    *reinterpret_cast<int4*>(&Bs[m][kq]) =
        *reinterpret_cast<const int4*>(&Bt[(size_t)(bn + m) * K + k0 + kq]);
    __syncthreads();
    const short8 a0 = *reinterpret_cast<short8*>(&As[w * 16 + r][g * 8]);
#pragma unroll
    for (int j = 0; j < 4; ++j) {
      const short8 b = *reinterpret_cast<short8*>(&Bs[j * 16 + r][g * 8]);
      acc[j] = __builtin_amdgcn_mfma_f32_16x16x32_bf16(a0, b, acc[j], 0, 0, 0);
    }
    __syncthreads();
  }
#pragma unroll
  for (int j = 0; j < 4; ++j)
#pragma unroll
    for (int q = 0; q < 4; ++q) {
      const int row = bm + w * 16 + g * 4 + q;
      const int col = bn + j * 16 + r;
      float v = acc[j][q];
      if (OUTMODE == 1) v = v >= 0.f ? v : 0.01f * v;
      Cb[(size_t)row * Nn + col] = __float2bfloat16(v);
    }
}

// ---------------- el/er: per-node per-head dots with attn vectors ------------
__global__ __launch_bounds__(256) void elr_kernel(const bf16* __restrict__ featb,
                                                  const float* __restrict__ attn_l,
                                                  const float* __restrict__ attn_r,
                                                  float* __restrict__ el,
                                                  float* __restrict__ er) {
  const int n = blockIdx.x;
  const int h = threadIdx.x >> 6, lane = threadIdx.x & 63;
  const uint2 v2 = *reinterpret_cast<const uint2*>(
      &featb[(size_t)n * FOUT + h * DHEAD + lane * 4]);
  const float f0 = bflo(v2.x), f1 = bfhi(v2.x), f2 = bflo(v2.y), f3 = bfhi(v2.y);
  const float4 al = *reinterpret_cast<const float4*>(&attn_l[h * DHEAD + lane * 4]);
  const float4 ar = *reinterpret_cast<const float4*>(&attn_r[h * DHEAD + lane * 4]);
  float sl = f0 * al.x + f1 * al.y + f2 * al.z + f3 * al.w;
  float sr = f0 * ar.x + f1 * ar.y + f2 * ar.z + f3 * ar.w;
  for (int off = 32; off; off >>= 1) {
    sl += __shfl_xor(sl, off);
    sr += __shfl_xor(sr, off);
  }
  if (lane == 0) {
    el[n * HEADS + h] = sl;
    er[n * HEADS + h] = sr;
  }
}

// ---------------- stream adj (skip simlar where adj==0), compact candidates --
__global__ __launch_bounds__(256) void stream_kernel(const float* __restrict__ adj,
                                                     const float* __restrict__ simlar,
                                                     int* __restrict__ rowcnt,
                                                     float* __restrict__ rowval,
                                                     int* __restrict__ rowidx) {
  int i = blockIdx.x * 256 + threadIdx.x;
  const int stride = gridDim.x * 256;
  const float4* adj4 = reinterpret_cast<const float4*>(adj);
  const float4* sim4 = reinterpret_cast<const float4*>(simlar);
  for (; i < N * N / 4; i += stride) {
    const float4 a4 = adj4[i];
    if (a4.x > 0.f || a4.y > 0.f || a4.z > 0.f || a4.w > 0.f) {
      const float4 s4 = sim4[i];
      const int s = i >> 10;  // N/4 = 1024 float4 per row
      const float aa[4] = {a4.x, a4.y, a4.z, a4.w};
      const float ss[4] = {s4.x, s4.y, s4.z, s4.w};
#pragma unroll
      for (int c = 0; c < 4; ++c) {
        if (aa[c] > 0.f && ss[c] > 0.f) {
          const int p = atomicAdd(&rowcnt[s], 1);
          if (p < CAP) {
            rowval[s * CAP + p] = ss[c];
            rowidx[s * CAP + p] = (i & 1023) * 4 + c;
          }
        }
      }
    }
  }
}

// ------- per-row top-29 rank select -> push source into column lists ---------
__global__ __launch_bounds__(64) void select_kernel(const int* __restrict__ rowcnt,
                                                    const float* __restrict__ rowval,
                                                    const int* __restrict__ rowidx,
                                                    int* __restrict__ colcnt,
                                                    int* __restrict__ colsrc) {
  const int s = blockIdx.x, t = threadIdx.x;
  __shared__ float v[CAP];
  const int C = min(rowcnt[s], CAP);
  if (t < C) v[t] = rowval[s * CAP + t];
  __syncthreads();
  if (t < C) {
    const float x = v[t];
    int rk = 0;
    for (int j = 0; j < C; ++j) rk += (v[j] > x);
    if (rk < TOPK) {
      const int d = rowidx[s * CAP + t];
      const int p = atomicAdd(&colcnt[d], 1);
      if (p < CAPC) colsrc[(size_t)d * CAPC + p] = s;
    }
  }
}

// ---------------- per-column softmax + weighted bf16 feature gather ----------
// 2 destination columns per block; 128 lanes per column, 8 dims per lane (16B).
__global__ __launch_bounds__(256) void agg_kernel(const int* __restrict__ colcnt,
                                                  const int* __restrict__ colsrc,
                                                  const float* __restrict__ el,
                                                  const float* __restrict__ er,
                                                  const bf16* __restrict__ featb,
                                                  const float* __restrict__ bias,
                                                  float* __restrict__ out) {
  __shared__ int tmp[2][CAPC];
  __shared__ int slist[2][CAPC];
  __shared__ float pbuf[2][HEADS][CAPC];
  const int t = threadIdx.x;
  const int grp = t >> 7;  // which of the 2 columns
  const int g = t & 127;   // lane within column group
  const int d = blockIdx.x * 2 + grp;
  const int C = min(colcnt[d], CAPC);
  if (g < C) tmp[grp][g] = colsrc[(size_t)d * CAPC + g];
  __syncthreads();
  // rank-sort ascending (unique ids -> bijective, deterministic vs atomics)
  if (g < C) {
    const int v = tmp[grp][g];
    int rk = 0;
    for (int j = 0; j < C; ++j) rk += (tmp[grp][j] < v);
    slist[grp][rk] = v;
  }
  __syncthreads();
  const int h = g >> 5;  // 4 heads x 32 lanes
  const int hl = g & 31;
  const float er_dh = er[d * HEADS + h];
  // pass A: e values -> pbuf, running max (32-lane head group)
  float m = -INFINITY;
  for (int i = hl; i < C; i += 32) {
    float e = el[slist[grp][i] * HEADS + h] + er_dh;
    e = e >= 0.f ? e : 0.2f * e;
    pbuf[grp][h][i] = e;
    m = fmaxf(m, e);
  }
#pragma unroll
  for (int off = 16; off; off >>= 1) m = fmaxf(m, __shfl_xor(m, off));
  // pass B: exp in place, denom reduce
  float dsum = 0.f;
  for (int i = hl; i < C; i += 32) {
    const float p = __expf(pbuf[grp][h][i] - m);
    pbuf[grp][h][i] = p;
    dsum += p;
  }
#pragma unroll
  for (int off = 16; off; off >>= 1) dsum += __shfl_xor(dsum, off);
  __syncthreads();
  // pass C: weighted gather of bf16 feat rows (128 lanes x 16B = 2KB/row)
  float acc[8] = {};
  for (int i = 0; i < C; ++i) {
    const float p = pbuf[grp][h][i];
    const uint4 v = *reinterpret_cast<const uint4*>(
        &featb[(size_t)slist[grp][i] * FOUT + g * 8]);
    acc[0] = fmaf(p, bflo(v.x), acc[0]);
    acc[1] = fmaf(p, bfhi(v.x), acc[1]);
    acc[2] = fmaf(p, bflo(v.y), acc[2]);
    acc[3] = fmaf(p, bfhi(v.y), acc[3]);
    acc[4] = fmaf(p, bflo(v.z), acc[4]);
    acc[5] = fmaf(p, bfhi(v.z), acc[5]);
    acc[6] = fmaf(p, bflo(v.w), acc[6]);
    acc[7] = fmaf(p, bfhi(v.w), acc[7]);
  }
  const float inv = C > 0 ? 1.f / dsum : 0.f;
  float o[8];
#pragma unroll
  for (int k = 0; k < 8; ++k) {
    const float r = acc[k] * inv + bias[g * 8 + k];
    o[k] = r > 0.f ? r : expm1f(r);
  }
  float* op = &out[(size_t)d * FOUT + g * 8];
  *reinterpret_cast<float4*>(op) = make_float4(o[0], o[1], o[2], o[3]);
  *reinterpret_cast<float4*>(op + 4) = make_float4(o[4], o[5], o[6], o[7]);
}

extern "C" void kernel_launch(void* const* d_in, const int* in_sizes, int n_in,
                              void* d_out, int out_size, void* d_ws, size_t ws_size,
                              hipStream_t stream) {
  const float* h        = (const float*)d_in[0];
  const float* simlar   = (const float*)d_in[1];
  const float* adj      = (const float*)d_in[2];
  const float* W_trans  = (const float*)d_in[3];
  const float* gat_W    = (const float*)d_in[4];
  const float* attn_l   = (const float*)d_in[5];
  const float* attn_r   = (const float*)d_in[6];
  const float* gat_bias = (const float*)d_in[7];
  // sem_W1 / sem_b1 / sem_W2 unused: beta = softmax over singleton == 1 -> out == sem.
  float* out = (float*)d_out;

  char* ws = (char*)d_ws;
  const size_t MB = 1 << 20;
  bf16* hb      = (bf16*)(ws);                        // 4 MB   (N x FIN)
  bf16* Wtb     = (bf16*)(ws + 4 * MB);               // 256 KB (HID x FIN)
  bf16* gWtb    = (bf16*)(ws + 4 * MB + 512 * 1024);  // 512 KB (FOUT x HID)
  bf16* xb      = (bf16*)(ws + 5 * MB);               // 2 MB   (N x HID)
  float* el     = (float*)(ws + 7 * MB);              // 64 KB
  float* er     = (float*)(ws + 7 * MB + 65536);      // 64 KB
  bf16* featb   = (bf16*)(ws + 8 * MB);               // 8 MB   (N x FOUT bf16)
  int* counters = (int*)(ws + 16 * MB);               // 32 KB (rowcnt | colcnt)
  float* rowval = (float*)(ws + 17 * MB);             // 1 MB
  int* rowidx   = (int*)(ws + 18 * MB);               // 1 MB
  int* colsrc   = (int*)(ws + 19 * MB);               // 1.5 MB
  int* rowcnt   = counters;
  int* colcnt   = counters + N;

  prep_kernel<<<2048, 256, 0, stream>>>(h, W_trans, gat_W, hb, Wtb, gWtb, counters);
  stream_kernel<<<2048, 256, 0, stream>>>(adj, simlar, rowcnt, rowval, rowidx);
  select_kernel<<<N, 64, 0, stream>>>(rowcnt, rowval, rowidx, colcnt, colsrc);
  gemm_mfma<1><<<dim3(N / 64, HID / 64), 256, 0, stream>>>(hb, Wtb, xb, N, HID, FIN);
  gemm_mfma<2><<<dim3(N / 64, FOUT / 64), 256, 0, stream>>>(xb, gWtb, featb, N, FOUT, HID);
  elr_kernel<<<N, 256, 0, stream>>>(featb, attn_l, attn_r, el, er);
  agg_kernel<<<N / 2, 256, 0, stream>>>(colcnt, colsrc, el, er, featb, gat_bias, out);
}

// Round 6
// 80.333 us; speedup vs baseline: 1.8146x; 1.1551x over previous
//
#include <hip/hip_runtime.h>
#include <hip/hip_bf16.h>
#include <math.h>

#define N 4096
#define FIN 512
#define HID 256
#define HEADS 4
#define DHEAD 256
#define FOUT 1024
#define TOPK 29
#define CAP 64    // per-row candidate capacity (mean ~20.5, sd ~4.5)
#define CAPC 96   // per-column source capacity (in-degree mean ~20.4)

typedef __attribute__((ext_vector_type(8))) short short8;
typedef __attribute__((ext_vector_type(4))) float f32x4;
typedef __hip_bfloat16 bf16;

__device__ __forceinline__ float bflo(unsigned int u) {
  return __uint_as_float(u << 16);
}
__device__ __forceinline__ float bfhi(unsigned int u) {
  return __uint_as_float(u & 0xffff0000u);
}

// ---- fused: bf16 conversions (phase 1) + wave-per-row adj scan, in-order ----
// ---- compaction via ballot/prefix, rank top-29, push to column lists -------
__global__ __launch_bounds__(256) void prep_scan_kernel(
    const float* __restrict__ h, const float* __restrict__ W_trans,
    const float* __restrict__ gat_W, const float* __restrict__ adj,
    const float* __restrict__ simlar, bf16* __restrict__ hb,
    bf16* __restrict__ Wtb, bf16* __restrict__ gWtb,
    int* __restrict__ colcnt, int* __restrict__ colsrc) {
  // ---- phase 1: grid-stride conversions ----
  const int H4 = N * FIN / 4;  // 524288 float4 of h
  const int WT = HID * FIN;    // 131072 Wtb elements [HID][FIN]
  const int GT = FOUT * HID;   // 262144 gWtb elements [FOUT][HID]
  const int total = H4 + WT + GT;
  const int stride = gridDim.x * 256;
  for (int i = blockIdx.x * 256 + threadIdx.x; i < total; i += stride) {
    if (i < H4) {
      const float4 v = reinterpret_cast<const float4*>(h)[i];
      bf16 tmp[4];
      tmp[0] = __float2bfloat16(v.x);
      tmp[1] = __float2bfloat16(v.y);
      tmp[2] = __float2bfloat16(v.z);
      tmp[3] = __float2bfloat16(v.w);
      *reinterpret_cast<ushort4*>(&hb[(size_t)i * 4]) = *reinterpret_cast<ushort4*>(tmp);
    } else if (i < H4 + WT) {
      const int j = i - H4;
      const int row = j >> 9, k = j & 511;  // [HID][FIN]
      Wtb[j] = __float2bfloat16(W_trans[(size_t)k * HID + row]);
    } else {
      const int j = i - H4 - WT;
      const int row = j >> 8, k = j & 255;  // [FOUT][HID]
      gWtb[j] = __float2bfloat16(gat_W[(size_t)k * FOUT + row]);
    }
  }
  // ---- phase 2: wave-per-row scan (gridDim.x == 1024 -> 4096 waves) ----
  __shared__ float swv[4][CAP];
  __shared__ int swi[4][CAP];
  const int wv = threadIdx.x >> 6, lane = threadIdx.x & 63;
  const int s = blockIdx.x * 4 + wv;
  const float4* adj4 = reinterpret_cast<const float4*>(adj) + (size_t)s * (N / 4);
  const float4* sim4 = reinterpret_cast<const float4*>(simlar) + (size_t)s * (N / 4);
  int base = 0;
  for (int it = 0; it < N / 4 / 64; ++it) {  // 16 iterations
    const int j = it * 64 + lane;
    const float4 a4 = adj4[j];
    float4 s4 = make_float4(0.f, 0.f, 0.f, 0.f);
    if (a4.x > 0.f || a4.y > 0.f || a4.z > 0.f || a4.w > 0.f) s4 = sim4[j];
    const float aa[4] = {a4.x, a4.y, a4.z, a4.w};
    const float ss[4] = {s4.x, s4.y, s4.z, s4.w};
#pragma unroll
    for (int c = 0; c < 4; ++c) {
      const bool hit = (aa[c] > 0.f) && (ss[c] > 0.f);
      const unsigned long long mask = __ballot(hit);
      if (hit) {
        const int pos = base + __popcll(mask & ((1ull << lane) - 1ull));
        if (pos < CAP) {
          swv[wv][pos] = ss[c];
          swi[wv][pos] = j * 4 + c;
        }
      }
      base += __popcll(mask);
    }
  }
  __syncthreads();  // make wave-filled LDS visible for the rank pass
  const int C = min(base, CAP);
  if (lane < C) {
    const float x = swv[wv][lane];
    int rk = 0;
    for (int jj = 0; jj < C; ++jj) rk += (swv[wv][jj] > x);
    if (rk < TOPK) {
      const int d = swi[wv][lane];
      const int p = atomicAdd(&colcnt[d], 1);
      if (p < CAPC) colsrc[(size_t)d * CAPC + p] = s;
    }
  }
}

// ---------------- bf16 MFMA GEMM: C[M x Nn] = A[M x K] @ Bt[Nn x K]^T --------
// BM=64, BN=64, BK=64, 256 threads (4 waves); wave w owns rows [w*16, w*16+16).
// OUTMODE 1: lrelu(0.01)+bf16 out; 2: plain bf16 out.
template <int OUTMODE>
__global__ __launch_bounds__(256) void gemm_mfma(const bf16* __restrict__ A,
                                                 const bf16* __restrict__ Bt,
                                                 bf16* __restrict__ Cb,
                                                 int M, int Nn, int K) {
  __shared__ bf16 As[64][72];  // +8 pad: 144B row stride (16B-aligned), 2-way max
  __shared__ bf16 Bs[64][72];
  const int t = threadIdx.x;
  const int bm = blockIdx.x * 64, bn = blockIdx.y * 64;
  const int w = t >> 6, lane = t & 63, r = lane & 15, g = lane >> 4;
  const int m = t >> 2, c0 = (t & 3) * 8;  // staging: 64 rows x 2x16B chunks each
  f32x4 acc[4] = {};
  for (int k0 = 0; k0 < K; k0 += 64) {
    const bf16* arow = &A[(size_t)(bm + m) * K + k0];
    const bf16* brow = &Bt[(size_t)(bn + m) * K + k0];
    *reinterpret_cast<int4*>(&As[m][c0]) = *reinterpret_cast<const int4*>(&arow[c0]);
    *reinterpret_cast<int4*>(&As[m][c0 + 32]) = *reinterpret_cast<const int4*>(&arow[c0 + 32]);
    *reinterpret_cast<int4*>(&Bs[m][c0]) = *reinterpret_cast<const int4*>(&brow[c0]);
    *reinterpret_cast<int4*>(&Bs[m][c0 + 32]) = *reinterpret_cast<const int4*>(&brow[c0 + 32]);
    __syncthreads();
    const short8 a0 = *reinterpret_cast<short8*>(&As[w * 16 + r][g * 8]);
    const short8 a1 = *reinterpret_cast<short8*>(&As[w * 16 + r][32 + g * 8]);
#pragma unroll
    for (int j = 0; j < 4; ++j) {
      const short8 b0 = *reinterpret_cast<short8*>(&Bs[j * 16 + r][g * 8]);
      const short8 b1 = *reinterpret_cast<short8*>(&Bs[j * 16 + r][32 + g * 8]);
      acc[j] = __builtin_amdgcn_mfma_f32_16x16x32_bf16(a0, b0, acc[j], 0, 0, 0);
      acc[j] = __builtin_amdgcn_mfma_f32_16x16x32_bf16(a1, b1, acc[j], 0, 0, 0);
    }
    __syncthreads();
  }
#pragma unroll
  for (int j = 0; j < 4; ++j)
#pragma unroll
    for (int q = 0; q < 4; ++q) {
      const int row = bm + w * 16 + g * 4 + q;
      const int col = bn + j * 16 + r;
      float v = acc[j][q];
      if (OUTMODE == 1) v = v >= 0.f ? v : 0.01f * v;
      Cb[(size_t)row * Nn + col] = __float2bfloat16(v);
    }
}

// ---------------- el/er: per-node per-head dots with attn vectors ------------
__global__ __launch_bounds__(256) void elr_kernel(const bf16* __restrict__ featb,
                                                  const float* __restrict__ attn_l,
                                                  const float* __restrict__ attn_r,
                                                  float* __restrict__ el,
                                                  float* __restrict__ er) {
  const int n = blockIdx.x;
  const int h = threadIdx.x >> 6, lane = threadIdx.x & 63;
  const uint2 v2 = *reinterpret_cast<const uint2*>(
      &featb[(size_t)n * FOUT + h * DHEAD + lane * 4]);
  const float f0 = bflo(v2.x), f1 = bfhi(v2.x), f2 = bflo(v2.y), f3 = bfhi(v2.y);
  const float4 al = *reinterpret_cast<const float4*>(&attn_l[h * DHEAD + lane * 4]);
  const float4 ar = *reinterpret_cast<const float4*>(&attn_r[h * DHEAD + lane * 4]);
  float sl = f0 * al.x + f1 * al.y + f2 * al.z + f3 * al.w;
  float sr = f0 * ar.x + f1 * ar.y + f2 * ar.z + f3 * ar.w;
  for (int off = 32; off; off >>= 1) {
    sl += __shfl_xor(sl, off);
    sr += __shfl_xor(sr, off);
  }
  if (lane == 0) {
    el[n * HEADS + h] = sl;
    er[n * HEADS + h] = sr;
  }
}

// ---------------- per-column softmax + weighted bf16 feature gather ----------
// 2 destination columns per block; 128 lanes per column, 8 dims per lane (16B).
__global__ __launch_bounds__(256) void agg_kernel(const int* __restrict__ colcnt,
                                                  const int* __restrict__ colsrc,
                                                  const float* __restrict__ el,
                                                  const float* __restrict__ er,
                                                  const bf16* __restrict__ featb,
                                                  const float* __restrict__ bias,
                                                  float* __restrict__ out) {
  __shared__ int tmp[2][CAPC];
  __shared__ int slist[2][CAPC];
  __shared__ float pbuf[2][HEADS][CAPC];
  const int t = threadIdx.x;
  const int grp = t >> 7;  // which of the 2 columns
  const int g = t & 127;   // lane within column group
  const int d = blockIdx.x * 2 + grp;
  const int C = min(colcnt[d], CAPC);
  if (g < C) tmp[grp][g] = colsrc[(size_t)d * CAPC + g];
  __syncthreads();
  // rank-sort ascending (unique ids -> bijective, deterministic vs atomics)
  if (g < C) {
    const int v = tmp[grp][g];
    int rk = 0;
    for (int j = 0; j < C; ++j) rk += (tmp[grp][j] < v);
    slist[grp][rk] = v;
  }
  __syncthreads();
  const int h = g >> 5;  // 4 heads x 32 lanes
  const int hl = g & 31;
  const float er_dh = er[d * HEADS + h];
  // pass A: e values -> pbuf, running max (32-lane head group)
  float m = -INFINITY;
  for (int i = hl; i < C; i += 32) {
    float e = el[slist[grp][i] * HEADS + h] + er_dh;
    e = e >= 0.f ? e : 0.2f * e;
    pbuf[grp][h][i] = e;
    m = fmaxf(m, e);
  }
#pragma unroll
  for (int off = 16; off; off >>= 1) m = fmaxf(m, __shfl_xor(m, off));
  // pass B: exp in place, denom reduce
  float dsum = 0.f;
  for (int i = hl; i < C; i += 32) {
    const float p = __expf(pbuf[grp][h][i] - m);
    pbuf[grp][h][i] = p;
    dsum += p;
  }
#pragma unroll
  for (int off = 16; off; off >>= 1) dsum += __shfl_xor(dsum, off);
  __syncthreads();
  // pass C: weighted gather of bf16 feat rows (128 lanes x 16B = 2KB/row),
  // unrolled x2 to keep two row loads in flight.
  float acc[8] = {};
  int i = 0;
  for (; i + 2 <= C; i += 2) {
    const float p0 = pbuf[grp][h][i];
    const float p1 = pbuf[grp][h][i + 1];
    const uint4 v0 = *reinterpret_cast<const uint4*>(
        &featb[(size_t)slist[grp][i] * FOUT + g * 8]);
    const uint4 v1 = *reinterpret_cast<const uint4*>(
        &featb[(size_t)slist[grp][i + 1] * FOUT + g * 8]);
    acc[0] = fmaf(p0, bflo(v0.x), acc[0]);
    acc[1] = fmaf(p0, bfhi(v0.x), acc[1]);
    acc[2] = fmaf(p0, bflo(v0.y), acc[2]);
    acc[3] = fmaf(p0, bfhi(v0.y), acc[3]);
    acc[4] = fmaf(p0, bflo(v0.z), acc[4]);
    acc[5] = fmaf(p0, bfhi(v0.z), acc[5]);
    acc[6] = fmaf(p0, bflo(v0.w), acc[6]);
    acc[7] = fmaf(p0, bfhi(v0.w), acc[7]);
    acc[0] = fmaf(p1, bflo(v1.x), acc[0]);
    acc[1] = fmaf(p1, bfhi(v1.x), acc[1]);
    acc[2] = fmaf(p1, bflo(v1.y), acc[2]);
    acc[3] = fmaf(p1, bfhi(v1.y), acc[3]);
    acc[4] = fmaf(p1, bflo(v1.z), acc[4]);
    acc[5] = fmaf(p1, bfhi(v1.z), acc[5]);
    acc[6] = fmaf(p1, bflo(v1.w), acc[6]);
    acc[7] = fmaf(p1, bfhi(v1.w), acc[7]);
  }
  if (i < C) {
    const float p0 = pbuf[grp][h][i];
    const uint4 v0 = *reinterpret_cast<const uint4*>(
        &featb[(size_t)slist[grp][i] * FOUT + g * 8]);
    acc[0] = fmaf(p0, bflo(v0.x), acc[0]);
    acc[1] = fmaf(p0, bfhi(v0.x), acc[1]);
    acc[2] = fmaf(p0, bflo(v0.y), acc[2]);
    acc[3] = fmaf(p0, bfhi(v0.y), acc[3]);
    acc[4] = fmaf(p0, bflo(v0.z), acc[4]);
    acc[5] = fmaf(p0, bfhi(v0.z), acc[5]);
    acc[6] = fmaf(p0, bflo(v0.w), acc[6]);
    acc[7] = fmaf(p0, bfhi(v0.w), acc[7]);
  }
  const float inv = C > 0 ? 1.f / dsum : 0.f;
  float o[8];
#pragma unroll
  for (int k = 0; k < 8; ++k) {
    const float r = acc[k] * inv + bias[g * 8 + k];
    o[k] = r > 0.f ? r : expm1f(r);
  }
  float* op = &out[(size_t)d * FOUT + g * 8];
  *reinterpret_cast<float4*>(op) = make_float4(o[0], o[1], o[2], o[3]);
  *reinterpret_cast<float4*>(op + 4) = make_float4(o[4], o[5], o[6], o[7]);
}

extern "C" void kernel_launch(void* const* d_in, const int* in_sizes, int n_in,
                              void* d_out, int out_size, void* d_ws, size_t ws_size,
                              hipStream_t stream) {
  const float* h        = (const float*)d_in[0];
  const float* simlar   = (const float*)d_in[1];
  const float* adj      = (const float*)d_in[2];
  const float* W_trans  = (const float*)d_in[3];
  const float* gat_W    = (const float*)d_in[4];
  const float* attn_l   = (const float*)d_in[5];
  const float* attn_r   = (const float*)d_in[6];
  const float* gat_bias = (const float*)d_in[7];
  // sem_W1 / sem_b1 / sem_W2 unused: beta = softmax over singleton == 1 -> out == sem.
  float* out = (float*)d_out;

  char* ws = (char*)d_ws;
  const size_t MB = 1 << 20;
  bf16* hb    = (bf16*)(ws);                        // 4 MB   (N x FIN)
  bf16* Wtb   = (bf16*)(ws + 4 * MB);               // 256 KB (HID x FIN)
  bf16* gWtb  = (bf16*)(ws + 4 * MB + 512 * 1024);  // 512 KB (FOUT x HID)
  bf16* xb    = (bf16*)(ws + 5 * MB);               // 2 MB   (N x HID)
  float* el   = (float*)(ws + 7 * MB);              // 64 KB
  float* er   = (float*)(ws + 7 * MB + 65536);      // 64 KB
  bf16* featb = (bf16*)(ws + 8 * MB);               // 8 MB   (N x FOUT bf16)
  int* colcnt = (int*)(ws + 16 * MB);               // 16 KB
  int* colsrc = (int*)(ws + 17 * MB);               // 1.5 MB

  hipMemsetAsync(colcnt, 0, (size_t)N * sizeof(int), stream);
  prep_scan_kernel<<<1024, 256, 0, stream>>>(h, W_trans, gat_W, adj, simlar,
                                             hb, Wtb, gWtb, colcnt, colsrc);
  gemm_mfma<1><<<dim3(N / 64, HID / 64), 256, 0, stream>>>(hb, Wtb, xb, N, HID, FIN);
  gemm_mfma<2><<<dim3(N / 64, FOUT / 64), 256, 0, stream>>>(xb, gWtb, featb, N, FOUT, HID);
  elr_kernel<<<N, 256, 0, stream>>>(featb, attn_l, attn_r, el, er);
  agg_kernel<<<N / 2, 256, 0, stream>>>(colcnt, colsrc, el, er, featb, gat_bias, out);
}

// Round 7
// 75.594 us; speedup vs baseline: 1.9283x; 1.0627x over previous
//
#include <hip/hip_runtime.h>
#include <hip/hip_bf16.h>
#include <math.h>

#define N 4096
#define FIN 512
#define HID 256
#define HEADS 4
#define DHEAD 256
#define FOUT 1024
#define TOPK 29
#define CAP 64    // per-row candidate capacity (mean ~20.5, sd ~4.5)
#define CAPC 96   // per-column source capacity (in-degree mean ~20.4)

typedef __attribute__((ext_vector_type(8))) short short8;
typedef __attribute__((ext_vector_type(4))) float f32x4;
typedef __hip_bfloat16 bf16;

__device__ __forceinline__ float bflo(unsigned int u) {
  return __uint_as_float(u << 16);
}
__device__ __forceinline__ float bfhi(unsigned int u) {
  return __uint_as_float(u & 0xffff0000u);
}

// ---- block-per-row scan + fused prep converts + fused top-29 select --------
// phase 0: grid-stride bf16 conversions (~1 elem/thread at 4096 blocks)
// phase 1: row scan; 4 independent adj4 loads/thread, cond sim4, LDS compaction
// phase 2: rank top-29 among positives, push source into column lists
__global__ __launch_bounds__(256) void scan_kernel(
    const float* __restrict__ h, const float* __restrict__ W_trans,
    const float* __restrict__ gat_W, const float* __restrict__ adj,
    const float* __restrict__ simlar, bf16* __restrict__ hb,
    bf16* __restrict__ Wtb, bf16* __restrict__ gWtb,
    int* __restrict__ colcnt, int* __restrict__ colsrc) {
  const int t = threadIdx.x;
  const int s = blockIdx.x;
  // ---- phase 0 ----
  {
    const int H4 = N * FIN / 4;  // 524288 float4 of h
    const int WT = HID * FIN;    // 131072 Wtb elements [HID][FIN]
    const int GT = FOUT * HID;   // 262144 gWtb elements [FOUT][HID]
    const int total = H4 + WT + GT;
    const int stride = gridDim.x * 256;
    for (int i = s * 256 + t; i < total; i += stride) {
      if (i < H4) {
        const float4 v = reinterpret_cast<const float4*>(h)[i];
        bf16 tmp[4];
        tmp[0] = __float2bfloat16(v.x);
        tmp[1] = __float2bfloat16(v.y);
        tmp[2] = __float2bfloat16(v.z);
        tmp[3] = __float2bfloat16(v.w);
        *reinterpret_cast<ushort4*>(&hb[(size_t)i * 4]) =
            *reinterpret_cast<ushort4*>(tmp);
      } else if (i < H4 + WT) {
        const int j = i - H4;
        const int row = j >> 9, k = j & 511;  // [HID][FIN]
        Wtb[j] = __float2bfloat16(W_trans[(size_t)k * HID + row]);
      } else {
        const int j = i - H4 - WT;
        const int row = j >> 8, k = j & 255;  // [FOUT][HID]
        gWtb[j] = __float2bfloat16(gat_W[(size_t)k * FOUT + row]);
      }
    }
  }
  // ---- phase 1: scan row s ----
  __shared__ float swv[CAP];
  __shared__ int swi[CAP];
  __shared__ int cnt;
  if (t == 0) cnt = 0;
  __syncthreads();
  const float4* rowadj = reinterpret_cast<const float4*>(adj) + (size_t)s * (N / 4);
  const float4* rowsim = reinterpret_cast<const float4*>(simlar) + (size_t)s * (N / 4);
  float4 a[4];
#pragma unroll
  for (int it = 0; it < 4; ++it) a[it] = rowadj[it * 256 + t];  // 4 loads in flight
#pragma unroll
  for (int it = 0; it < 4; ++it) {
    const int j = it * 256 + t;
    if (a[it].x > 0.f || a[it].y > 0.f || a[it].z > 0.f || a[it].w > 0.f) {
      const float4 s4 = rowsim[j];
      const float aa[4] = {a[it].x, a[it].y, a[it].z, a[it].w};
      const float ss[4] = {s4.x, s4.y, s4.z, s4.w};
#pragma unroll
      for (int c = 0; c < 4; ++c) {
        if (aa[c] > 0.f && ss[c] > 0.f) {
          const int p = atomicAdd(&cnt, 1);
          if (p < CAP) {
            swv[p] = ss[c];
            swi[p] = j * 4 + c;
          }
        }
      }
    }
  }
  __syncthreads();
  // ---- phase 2: rank select (value-based -> order-independent) ----
  const int C = min(cnt, CAP);
  if (t < C) {
    const float x = swv[t];
    int rk = 0;
    for (int jj = 0; jj < C; ++jj) rk += (swv[jj] > x);
    if (rk < TOPK) {
      const int d = swi[t];
      const int p = atomicAdd(&colcnt[d], 1);
      if (p < CAPC) colsrc[(size_t)d * CAPC + p] = s;
    }
  }
}

// ---------------- bf16 MFMA GEMM: C[M x Nn] = A[M x K] @ Bt[Nn x K]^T --------
// BM=64, BN=64, BK=64, 256 threads (4 waves); wave w owns rows [w*16, w*16+16).
// OUTMODE 1: lrelu(0.01)+bf16 out; 2: plain bf16 out.
template <int OUTMODE>
__global__ __launch_bounds__(256) void gemm_mfma(const bf16* __restrict__ A,
                                                 const bf16* __restrict__ Bt,
                                                 bf16* __restrict__ Cb,
                                                 int M, int Nn, int K) {
  __shared__ bf16 As[64][72];  // +8 pad: 144B row stride (16B-aligned), 2-way max
  __shared__ bf16 Bs[64][72];
  const int t = threadIdx.x;
  const int bm = blockIdx.x * 64, bn = blockIdx.y * 64;
  const int w = t >> 6, lane = t & 63, r = lane & 15, g = lane >> 4;
  const int m = t >> 2, c0 = (t & 3) * 8;  // staging: 64 rows x 2x16B chunks each
  f32x4 acc[4] = {};
  for (int k0 = 0; k0 < K; k0 += 64) {
    const bf16* arow = &A[(size_t)(bm + m) * K + k0];
    const bf16* brow = &Bt[(size_t)(bn + m) * K + k0];
    *reinterpret_cast<int4*>(&As[m][c0]) = *reinterpret_cast<const int4*>(&arow[c0]);
    *reinterpret_cast<int4*>(&As[m][c0 + 32]) = *reinterpret_cast<const int4*>(&arow[c0 + 32]);
    *reinterpret_cast<int4*>(&Bs[m][c0]) = *reinterpret_cast<const int4*>(&brow[c0]);
    *reinterpret_cast<int4*>(&Bs[m][c0 + 32]) = *reinterpret_cast<const int4*>(&brow[c0 + 32]);
    __syncthreads();
    const short8 a0 = *reinterpret_cast<short8*>(&As[w * 16 + r][g * 8]);
    const short8 a1 = *reinterpret_cast<short8*>(&As[w * 16 + r][32 + g * 8]);
#pragma unroll
    for (int j = 0; j < 4; ++j) {
      const short8 b0 = *reinterpret_cast<short8*>(&Bs[j * 16 + r][g * 8]);
      const short8 b1 = *reinterpret_cast<short8*>(&Bs[j * 16 + r][32 + g * 8]);
      acc[j] = __builtin_amdgcn_mfma_f32_16x16x32_bf16(a0, b0, acc[j], 0, 0, 0);
      acc[j] = __builtin_amdgcn_mfma_f32_16x16x32_bf16(a1, b1, acc[j], 0, 0, 0);
    }
    __syncthreads();
  }
#pragma unroll
  for (int j = 0; j < 4; ++j)
#pragma unroll
    for (int q = 0; q < 4; ++q) {
      const int row = bm + w * 16 + g * 4 + q;
      const int col = bn + j * 16 + r;
      float v = acc[j][q];
      if (OUTMODE == 1) v = v >= 0.f ? v : 0.01f * v;
      Cb[(size_t)row * Nn + col] = __float2bfloat16(v);
    }
}

// ---------------- el/er: per-node per-head dots with attn vectors ------------
__global__ __launch_bounds__(256) void elr_kernel(const bf16* __restrict__ featb,
                                                  const float* __restrict__ attn_l,
                                                  const float* __restrict__ attn_r,
                                                  float* __restrict__ el,
                                                  float* __restrict__ er) {
  const int n = blockIdx.x;
  const int h = threadIdx.x >> 6, lane = threadIdx.x & 63;
  const uint2 v2 = *reinterpret_cast<const uint2*>(
      &featb[(size_t)n * FOUT + h * DHEAD + lane * 4]);
  const float f0 = bflo(v2.x), f1 = bfhi(v2.x), f2 = bflo(v2.y), f3 = bfhi(v2.y);
  const float4 al = *reinterpret_cast<const float4*>(&attn_l[h * DHEAD + lane * 4]);
  const float4 ar = *reinterpret_cast<const float4*>(&attn_r[h * DHEAD + lane * 4]);
  float sl = f0 * al.x + f1 * al.y + f2 * al.z + f3 * al.w;
  float sr = f0 * ar.x + f1 * ar.y + f2 * ar.z + f3 * ar.w;
  for (int off = 32; off; off >>= 1) {
    sl += __shfl_xor(sl, off);
    sr += __shfl_xor(sr, off);
  }
  if (lane == 0) {
    el[n * HEADS + h] = sl;
    er[n * HEADS + h] = sr;
  }
}

// ---------------- per-column softmax + weighted bf16 feature gather ----------
// 2 destination columns per block; 128 lanes per column, 8 dims per lane (16B).
__global__ __launch_bounds__(256) void agg_kernel(const int* __restrict__ colcnt,
                                                  const int* __restrict__ colsrc,
                                                  const float* __restrict__ el,
                                                  const float* __restrict__ er,
                                                  const bf16* __restrict__ featb,
                                                  const float* __restrict__ bias,
                                                  float* __restrict__ out) {
  __shared__ int tmp[2][CAPC];
  __shared__ int slist[2][CAPC];
  __shared__ float pbuf[2][HEADS][CAPC];
  const int t = threadIdx.x;
  const int grp = t >> 7;  // which of the 2 columns
  const int g = t & 127;   // lane within column group
  const int d = blockIdx.x * 2 + grp;
  const int C = min(colcnt[d], CAPC);
  if (g < C) tmp[grp][g] = colsrc[(size_t)d * CAPC + g];
  __syncthreads();
  // rank-sort ascending (unique ids -> bijective, deterministic vs atomics)
  if (g < C) {
    const int v = tmp[grp][g];
    int rk = 0;
    for (int j = 0; j < C; ++j) rk += (tmp[grp][j] < v);
    slist[grp][rk] = v;
  }
  __syncthreads();
  const int h = g >> 5;  // 4 heads x 32 lanes
  const int hl = g & 31;
  const float er_dh = er[d * HEADS + h];
  // pass A: e values -> pbuf, running max (32-lane head group)
  float m = -INFINITY;
  for (int i = hl; i < C; i += 32) {
    float e = el[slist[grp][i] * HEADS + h] + er_dh;
    e = e >= 0.f ? e : 0.2f * e;
    pbuf[grp][h][i] = e;
    m = fmaxf(m, e);
  }
#pragma unroll
  for (int off = 16; off; off >>= 1) m = fmaxf(m, __shfl_xor(m, off));
  // pass B: exp in place, denom reduce
  float dsum = 0.f;
  for (int i = hl; i < C; i += 32) {
    const float p = __expf(pbuf[grp][h][i] - m);
    pbuf[grp][h][i] = p;
    dsum += p;
  }
#pragma unroll
  for (int off = 16; off; off >>= 1) dsum += __shfl_xor(dsum, off);
  __syncthreads();
  // pass C: weighted gather of bf16 feat rows (128 lanes x 16B = 2KB/row),
  // unrolled x2 to keep two row loads in flight.
  float acc[8] = {};
  int i = 0;
  for (; i + 2 <= C; i += 2) {
    const float p0 = pbuf[grp][h][i];
    const float p1 = pbuf[grp][h][i + 1];
    const uint4 v0 = *reinterpret_cast<const uint4*>(
        &featb[(size_t)slist[grp][i] * FOUT + g * 8]);
    const uint4 v1 = *reinterpret_cast<const uint4*>(
        &featb[(size_t)slist[grp][i + 1] * FOUT + g * 8]);
    acc[0] = fmaf(p0, bflo(v0.x), acc[0]);
    acc[1] = fmaf(p0, bfhi(v0.x), acc[1]);
    acc[2] = fmaf(p0, bflo(v0.y), acc[2]);
    acc[3] = fmaf(p0, bfhi(v0.y), acc[3]);
    acc[4] = fmaf(p0, bflo(v0.z), acc[4]);
    acc[5] = fmaf(p0, bfhi(v0.z), acc[5]);
    acc[6] = fmaf(p0, bflo(v0.w), acc[6]);
    acc[7] = fmaf(p0, bfhi(v0.w), acc[7]);
    acc[0] = fmaf(p1, bflo(v1.x), acc[0]);
    acc[1] = fmaf(p1, bfhi(v1.x), acc[1]);
    acc[2] = fmaf(p1, bflo(v1.y), acc[2]);
    acc[3] = fmaf(p1, bfhi(v1.y), acc[3]);
    acc[4] = fmaf(p1, bflo(v1.z), acc[4]);
    acc[5] = fmaf(p1, bfhi(v1.z), acc[5]);
    acc[6] = fmaf(p1, bflo(v1.w), acc[6]);
    acc[7] = fmaf(p1, bfhi(v1.w), acc[7]);
  }
  if (i < C) {
    const float p0 = pbuf[grp][h][i];
    const uint4 v0 = *reinterpret_cast<const uint4*>(
        &featb[(size_t)slist[grp][i] * FOUT + g * 8]);
    acc[0] = fmaf(p0, bflo(v0.x), acc[0]);
    acc[1] = fmaf(p0, bfhi(v0.x), acc[1]);
    acc[2] = fmaf(p0, bflo(v0.y), acc[2]);
    acc[3] = fmaf(p0, bfhi(v0.y), acc[3]);
    acc[4] = fmaf(p0, bflo(v0.z), acc[4]);
    acc[5] = fmaf(p0, bfhi(v0.z), acc[5]);
    acc[6] = fmaf(p0, bflo(v0.w), acc[6]);
    acc[7] = fmaf(p0, bfhi(v0.w), acc[7]);
  }
  const float inv = C > 0 ? 1.f / dsum : 0.f;
  float o[8];
#pragma unroll
  for (int k = 0; k < 8; ++k) {
    const float r = acc[k] * inv + bias[g * 8 + k];
    o[k] = r > 0.f ? r : expm1f(r);
  }
  float* op = &out[(size_t)d * FOUT + g * 8];
  *reinterpret_cast<float4*>(op) = make_float4(o[0], o[1], o[2], o[3]);
  *reinterpret_cast<float4*>(op + 4) = make_float4(o[4], o[5], o[6], o[7]);
}

extern "C" void kernel_launch(void* const* d_in, const int* in_sizes, int n_in,
                              void* d_out, int out_size, void* d_ws, size_t ws_size,
                              hipStream_t stream) {
  const float* h        = (const float*)d_in[0];
  const float* simlar   = (const float*)d_in[1];
  const float* adj      = (const float*)d_in[2];
  const float* W_trans  = (const float*)d_in[3];
  const float* gat_W    = (const float*)d_in[4];
  const float* attn_l   = (const float*)d_in[5];
  const float* attn_r   = (const float*)d_in[6];
  const float* gat_bias = (const float*)d_in[7];
  // sem_W1 / sem_b1 / sem_W2 unused: beta = softmax over singleton == 1 -> out == sem.
  float* out = (float*)d_out;

  char* ws = (char*)d_ws;
  const size_t MB = 1 << 20;
  bf16* hb    = (bf16*)(ws);                        // 4 MB   (N x FIN)
  bf16* Wtb   = (bf16*)(ws + 4 * MB);               // 256 KB (HID x FIN)
  bf16* gWtb  = (bf16*)(ws + 4 * MB + 512 * 1024);  // 512 KB (FOUT x HID)
  bf16* xb    = (bf16*)(ws + 5 * MB);               // 2 MB   (N x HID)
  float* el   = (float*)(ws + 7 * MB);              // 64 KB
  float* er   = (float*)(ws + 7 * MB + 65536);      // 64 KB
  bf16* featb = (bf16*)(ws + 8 * MB);               // 8 MB   (N x FOUT bf16)
  int* colcnt = (int*)(ws + 16 * MB);               // 16 KB
  int* colsrc = (int*)(ws + 17 * MB);               // 1.5 MB

  hipMemsetAsync(colcnt, 0, (size_t)N * sizeof(int), stream);
  scan_kernel<<<N, 256, 0, stream>>>(h, W_trans, gat_W, adj, simlar,
                                     hb, Wtb, gWtb, colcnt, colsrc);
  gemm_mfma<1><<<dim3(N / 64, HID / 64), 256, 0, stream>>>(hb, Wtb, xb, N, HID, FIN);
  gemm_mfma<2><<<dim3(N / 64, FOUT / 64), 256, 0, stream>>>(xb, gWtb, featb, N, FOUT, HID);
  elr_kernel<<<N, 256, 0, stream>>>(featb, attn_l, attn_r, el, er);
  agg_kernel<<<N / 2, 256, 0, stream>>>(colcnt, colsrc, el, er, featb, gat_bias, out);
}